// Round 3
// baseline (10997.013 us; speedup 1.0000x reference)
//
#include <hip/hip_runtime.h>

// liGRU on MI355X.
// Phase 1: P[64000][2048](bf16, in d_out) = x @ [Wh;Wz]^T + column sums/sumsq.
// Phase 2: persistent scan, 8 groups (4 batch rows each) x 16 WGs.
//          WGs self-organize into XCD-local groups (HW_REG_XCC_ID + atomics);
//          if regular (16 WGs/XCD) the h-record exchange uses volatile (sc0)
//          loads/stores that stay coherent in the XCD's own L2 (~200cy) instead
//          of system-scope L3 (~2000cy). Irregular placement -> uniform fallback
//          to system-scope (correct on any placement).
//          Records: u64 { tag=t+1 (hi32) | 2x bf16 h (lo32) } -- flag IS the data.
//          z-gate and candidate merged into the same wave (both U slices in
//          VGPRs) -> one raw s_barrier per step. P prefetched via
//          global_load_lds (wave 0, 3-slot rotation, depth 2).

#define T_STEPS 2000
#define NCOLS   2048
#define PKEEP   0.8f
#define BN_EPSF 1e-5f
#define NW      128
#define WPG     16

typedef __attribute__((ext_vector_type(8))) short bf16x8;
typedef __attribute__((ext_vector_type(4))) float f32x4;
typedef __attribute__((ext_vector_type(4))) unsigned int u32x4;

static __device__ __forceinline__ unsigned short f2bf(float f) {
  unsigned u = __builtin_bit_cast(unsigned, f);
  unsigned r = u + 0x7FFFu + ((u >> 16) & 1u);   // RNE
  return (unsigned short)(r >> 16);
}
static __device__ __forceinline__ float bf2f(unsigned short s) {
  unsigned u = ((unsigned)s) << 16;
  return __builtin_bit_cast(float, u);
}

// ---------------- K1: convert [Wh;Wz] f32 -> bf16 ----------------
__global__ void k_convw(const float* __restrict__ Wh, const float* __restrict__ Wz,
                        unsigned short* __restrict__ Wb) {
  int i = blockIdx.x * 256 + threadIdx.x;
  int e = i * 4;
  int n = e >> 9;
  int k = e & 511;
  const float* src = (n < 1024) ? (Wh + (size_t)n * 512 + k)
                                : (Wz + (size_t)(n - 1024) * 512 + k);
  float4 v = *(const float4*)src;
  *(ushort4*)(Wb + e) = make_ushort4(f2bf(v.x), f2bf(v.y), f2bf(v.z), f2bf(v.w));
}

// ---------------- K2: GEMM  P = x @ Wb^T  (+ BN stats) ----------------
__global__ __launch_bounds__(256, 2) void k_gemm(
    const float* __restrict__ X, const unsigned short* __restrict__ Wb,
    unsigned short* __restrict__ P, float* __restrict__ sums, float* __restrict__ sumsq) {
  __shared__ __align__(16) unsigned short As[128 * 32];
  __shared__ __align__(16) unsigned short Bs[128 * 32];
  const int tid  = threadIdx.x;
  const int bm   = blockIdx.x >> 4, bn = blockIdx.x & 15;
  const int lane = tid & 63, wid = tid >> 6;
  const int wm   = wid >> 1, wn = wid & 1;
  const int lrow = lane & 15, lk = lane >> 4;

  f32x4 acc[4][4] = {};

  for (int kk = 0; kk < 512; kk += 32) {
    __syncthreads();
#pragma unroll
    for (int j = 0; j < 2; ++j) {
      int c = j * 256 + wid * 64 + lane;
      int brow = c >> 2, b8 = (c & 3) * 8;
      const unsigned short* gp = Wb + (size_t)(bn * 128 + brow) * 512 + kk + b8;
      __builtin_amdgcn_global_load_lds(
          (const __attribute__((address_space(1))) unsigned int*)gp,
          (__attribute__((address_space(3))) unsigned int*)(Bs + (size_t)(j * 256 + wid * 64) * 8),
          16, 0, 0);
    }
    {
      int arow = tid >> 1, ahalf = tid & 1;
      const float4* xp = (const float4*)(X + (size_t)(bm * 128 + arow) * 512 + kk + ahalf * 16);
      unsigned v[8];
#pragma unroll
      for (int j = 0; j < 4; ++j) {
        float4 f = xp[j];
        v[j * 2 + 0] = (unsigned)f2bf(f.x) | ((unsigned)f2bf(f.y) << 16);
        v[j * 2 + 1] = (unsigned)f2bf(f.z) | ((unsigned)f2bf(f.w) << 16);
      }
      u32x4* ap = (u32x4*)(As + arow * 32 + ahalf * 16);
      u32x4 t0 = {v[0], v[1], v[2], v[3]};
      u32x4 t1 = {v[4], v[5], v[6], v[7]};
      ap[0] = t0; ap[1] = t1;
    }
    __syncthreads();

    bf16x8 af[4], bfr[4];
#pragma unroll
    for (int mt = 0; mt < 4; ++mt)
      af[mt] = *(const bf16x8*)(As + (wm * 64 + mt * 16 + lrow) * 32 + lk * 8);
#pragma unroll
    for (int nt = 0; nt < 4; ++nt)
      bfr[nt] = *(const bf16x8*)(Bs + (wn * 64 + nt * 16 + lrow) * 32 + lk * 8);
#pragma unroll
    for (int mt = 0; mt < 4; ++mt)
#pragma unroll
      for (int nt = 0; nt < 4; ++nt)
        acc[mt][nt] = __builtin_amdgcn_mfma_f32_16x16x32_bf16(af[mt], bfr[nt], acc[mt][nt], 0, 0, 0);
  }

#pragma unroll
  for (int mt = 0; mt < 4; ++mt)
#pragma unroll
    for (int nt = 0; nt < 4; ++nt) {
      f32x4 a = acc[mt][nt];
      int gcol  = bn * 128 + wn * 64 + nt * 16 + lrow;
      int grow0 = bm * 128 + wm * 64 + mt * 16 + lk * 4;
#pragma unroll
      for (int rr = 0; rr < 4; ++rr)
        P[(size_t)(grow0 + rr) * NCOLS + gcol] = f2bf(a[rr]);
    }
#pragma unroll
  for (int nt = 0; nt < 4; ++nt) {
    float s = 0.f, q = 0.f;
#pragma unroll
    for (int mt = 0; mt < 4; ++mt) {
      f32x4 a = acc[mt][nt];
#pragma unroll
      for (int rr = 0; rr < 4; ++rr) { s += a[rr]; q += a[rr] * a[rr]; }
    }
    s += __shfl_xor(s, 16); s += __shfl_xor(s, 32);
    q += __shfl_xor(q, 16); q += __shfl_xor(q, 32);
    if (lane < 16) {
      int gcol = bn * 128 + wn * 64 + nt * 16 + lrow;
      atomicAdd(&sums[gcol], s);
      atomicAdd(&sumsq[gcol], q);
    }
  }
}

// ---------------- K3: persistent scan ----------------
// ctrl: [0..15]=per-XCD counter, [16]=done, [17]=grank, [18]=ready
__global__ __launch_bounds__(256, 1) void k_scan(
    const float* __restrict__ Uh, const float* __restrict__ Uz,
    const float* __restrict__ gwh, const float* __restrict__ bwh,
    const float* __restrict__ gwz, const float* __restrict__ bwz,
    const unsigned short* P,            // aliases d_out (bf16 view) -- no restrict!
    const float* __restrict__ sums, const float* __restrict__ sumsq,
    unsigned long long* hrec,           // [8][2][2048] u64 records
    unsigned int* ctrl,
    float* out)                         // aliases d_out (f32 view) -- no restrict!
{
  __shared__ __align__(16) unsigned char hlds[8192];  // h_prev [4][1024] bf16, XOR-swizzled
  __shared__ __align__(16) unsigned char plds[3072];  // P staging, 3 x 1KB slots
  __shared__ int sgrp[3];                             // group, role, fast

  const int tid  = threadIdx.x;
  const int lane = tid & 63;
  const int wid  = tid >> 6;
  const int lrow = lane & 15, lk = lane >> 4;

  // ---- self-organize into XCD-local groups ----
  if (tid == 0) {
    unsigned xcc;
    asm volatile("s_getreg_b32 %0, hwreg(HW_REG_XCC_ID)" : "=s"(xcc));
    xcc &= 15u;
    unsigned idx = atomicAdd(&ctrl[xcc], 1u);
    __hip_atomic_fetch_add(&ctrl[16], 1u, __ATOMIC_RELEASE, __HIP_MEMORY_SCOPE_SYSTEM);
    while (__hip_atomic_load(&ctrl[16], __ATOMIC_RELAXED, __HIP_MEMORY_SCOPE_SYSTEM) < NW)
      __builtin_amdgcn_s_sleep(8);
    __builtin_amdgcn_fence(__ATOMIC_ACQUIRE, "agent");
    bool reg = (xcc < 8u) && (idx < WPG);
    if (reg)
      for (int i = 0; i < 8; ++i)
        reg = reg && (__hip_atomic_load(&ctrl[i], __ATOMIC_RELAXED,
                                        __HIP_MEMORY_SCOPE_SYSTEM) == WPG);
    if (reg) {
      sgrp[0] = (int)xcc; sgrp[1] = (int)idx; sgrp[2] = 1;
    } else {
      unsigned rank = atomicAdd(&ctrl[17], 1u);
      sgrp[0] = (int)(rank & 7u); sgrp[1] = (int)(rank >> 3); sgrp[2] = 0;
    }
  }
  __syncthreads();
  const int  g     = sgrp[0];
  const int  role  = sgrp[1];
  const bool fastp = (sgrp[2] != 0);
  const int  b0    = g * 4;
  const int  wu    = wid * 16 + lrow;      // unit within WG [0,64)
  const int  uu    = role * 64 + wu;       // global unit [0,1024)

  // ---- BatchNorm coefficients for h-col (uu) and z-col (1024+uu) ----
  float sclh, biah, sclz, biaz;
  {
    float s = sums[uu], q = sumsq[uu];
    float mean = s * (1.0f / 64000.0f);
    float var  = q * (1.0f / 64000.0f) - mean * mean;
    float rstd = rsqrtf(var + BN_EPSF);
    sclh = gwh[uu] * rstd; biah = bwh[uu] - mean * sclh;
    s = sums[1024 + uu]; q = sumsq[1024 + uu];
    mean = s * (1.0f / 64000.0f);
    var  = q * (1.0f / 64000.0f) - mean * mean;
    rstd = rsqrtf(var + BN_EPSF);
    sclz = gwz[uu] * rstd; biaz = bwz[uu] - mean * sclz;
  }

  // ---- preload both U rows (x PKEEP) as MFMA B-fragments (256 VGPRs) ----
  bf16x8 bh[32], bz[32];
  {
    const float* uhrow = Uh + (size_t)uu * 1024;
    const float* uzrow = Uz + (size_t)uu * 1024;
#pragma unroll
    for (int kt = 0; kt < 32; ++kt) {
      const float4* p4 = (const float4*)(uhrow + kt * 32 + lk * 8);
      float4 fa = p4[0], fb = p4[1];
      bf16x8 tv;
      tv[0] = (short)f2bf(fa.x * PKEEP); tv[1] = (short)f2bf(fa.y * PKEEP);
      tv[2] = (short)f2bf(fa.z * PKEEP); tv[3] = (short)f2bf(fa.w * PKEEP);
      tv[4] = (short)f2bf(fb.x * PKEEP); tv[5] = (short)f2bf(fb.y * PKEEP);
      tv[6] = (short)f2bf(fb.z * PKEEP); tv[7] = (short)f2bf(fb.w * PKEEP);
      bh[kt] = tv;
      const float4* q4 = (const float4*)(uzrow + kt * 32 + lk * 8);
      fa = q4[0]; fb = q4[1];
      tv[0] = (short)f2bf(fa.x * PKEEP); tv[1] = (short)f2bf(fa.y * PKEEP);
      tv[2] = (short)f2bf(fa.z * PKEEP); tv[3] = (short)f2bf(fa.w * PKEEP);
      tv[4] = (short)f2bf(fb.x * PKEEP); tv[5] = (short)f2bf(fb.y * PKEEP);
      tv[6] = (short)f2bf(fb.z * PKEEP); tv[7] = (short)f2bf(fb.w * PKEEP);
      bz[kt] = tv;
    }
  }

  // ---- initial P[0], P[1] -> plds slots 0,1 (wave 0, global_load_lds) ----
  if (wid == 0) {
#pragma unroll
    for (int tt = 0; tt < 2; ++tt) {
      int seg = lane >> 3, sub = lane & 7;
      int rr = seg & 3, gate = seg >> 2;
      const unsigned short* src = P + (size_t)(tt * 32 + b0 + rr) * NCOLS
                                  + gate * 1024 + role * 64 + sub * 8;
      __builtin_amdgcn_global_load_lds(
          (const __attribute__((address_space(1))) unsigned int*)src,
          (__attribute__((address_space(3))) unsigned int*)(plds + tt * 1024),
          16, 0, 0);
    }
  }
  __syncthreads();   // compiler drains vmcnt before barrier -> P[0],P[1] in LDS

  // ---- rendezvous 2: every WG's initial P loads drained (WAR on d_out) ----
  if (tid == 0) {
    __hip_atomic_fetch_add(&ctrl[18], 1u, __ATOMIC_RELEASE, __HIP_MEMORY_SCOPE_SYSTEM);
    while (__hip_atomic_load(&ctrl[18], __ATOMIC_RELAXED, __HIP_MEMORY_SCOPE_SYSTEM) < NW)
      __builtin_amdgcn_s_sleep(8);
  }
  __syncthreads();

  f32x4 hown = {0.f, 0.f, 0.f, 0.f};
  int cur = 0;   // t % 3

  for (int t = 0; t < T_STEPS; ++t) {
    // 1. poll 8 records (parity t&1); tag carries the data
    const unsigned long long* rb = hrec + (((size_t)(g * 2 + (t & 1))) << 11);
    unsigned long long rec[8];
#pragma unroll
    for (int j = 0; j < 8; ++j)
      rec[j] = fastp ? *(volatile const unsigned long long*)(rb + tid + 256 * j)
                     : __hip_atomic_load(rb + tid + 256 * j, __ATOMIC_RELAXED,
                                         __HIP_MEMORY_SCOPE_SYSTEM);
    while (true) {
      unsigned bad = 0;
#pragma unroll
      for (int j = 0; j < 8; ++j)
        if ((unsigned)(rec[j] >> 32) < (unsigned)t) bad |= (1u << j);
      if (__ballot(bad != 0) == 0ull) break;
      __builtin_amdgcn_s_sleep(1);
#pragma unroll
      for (int j = 0; j < 8; ++j)
        if (bad & (1u << j))
          rec[j] = fastp ? *(volatile const unsigned long long*)(rb + tid + 256 * j)
                         : __hip_atomic_load(rb + tid + 256 * j, __ATOMIC_RELAXED,
                                             __HIP_MEMORY_SCOPE_SYSTEM);
    }

    // 2. wave 0: prefetch P[t+2] -> plds slot (t+2)%3 (rides across barriers)
    if (wid == 0 && t + 2 < T_STEPS) {
      int nx2 = cur + 2; if (nx2 >= 3) nx2 -= 3;
      int seg = lane >> 3, sub = lane & 7;
      int rr = seg & 3, gate = seg >> 2;
      const unsigned short* src = P + (size_t)((t + 2) * 32 + b0 + rr) * NCOLS
                                  + gate * 1024 + role * 64 + sub * 8;
      __builtin_amdgcn_global_load_lds(
          (const __attribute__((address_space(1))) unsigned int*)src,
          (__attribute__((address_space(3))) unsigned int*)(plds + nx2 * 1024),
          16, 0, 0);
    }

    // 3. unpack h records to LDS (XOR-swizzled)
#pragma unroll
    for (int j = 0; j < 8; ++j) {
      int idx = tid + 256 * j;
      int row = idx >> 9, up = idx & 511;
      int byteoff = (row * 2048 + up * 4) ^ ((row & 3) << 5);
      *(unsigned*)(hlds + byteoff) = (unsigned)rec[j];
    }
    // raw barrier: only LDS drained -- P prefetch stays in flight
    asm volatile("s_waitcnt lgkmcnt(0)" ::: "memory");
    __builtin_amdgcn_sched_barrier(0);
    __builtin_amdgcn_s_barrier();
    asm volatile("" ::: "memory");

    // 4. both gates' dots; af fragment shared
    f32x4 ah0 = {0.f, 0.f, 0.f, 0.f}, ah1 = ah0, az0 = ah0, az1 = ah0;
#pragma unroll
    for (int kt = 0; kt < 32; ++kt) {
      int ab = ((lane & 3) * 2048 + kt * 64 + lk * 16) ^ ((lane & 3) << 5);
      bf16x8 af = *(const bf16x8*)(hlds + ab);
      if (kt & 1) {
        az1 = __builtin_amdgcn_mfma_f32_16x16x32_bf16(af, bz[kt], az1, 0, 0, 0);
        ah1 = __builtin_amdgcn_mfma_f32_16x16x32_bf16(af, bh[kt], ah1, 0, 0, 0);
      } else {
        az0 = __builtin_amdgcn_mfma_f32_16x16x32_bf16(af, bz[kt], az0, 0, 0, 0);
        ah0 = __builtin_amdgcn_mfma_f32_16x16x32_bf16(af, bh[kt], ah0, 0, 0, 0);
      }
    }

    // 5. epilogue (valid lanes 0..15 = batch rows 0..3 in regs)
    const unsigned short* pl = (const unsigned short*)(plds + cur * 1024);
    float hn4[4], on4[4];
    {
      f32x4 dh = ah0 + ah1, dz = az0 + az1;
#pragma unroll
      for (int rr = 0; rr < 4; ++rr) {
        float prh = dh[rr] + bf2f(pl[rr * 64 + wu]) * sclh + biah;
        float prz = dz[rr] + bf2f(pl[(4 + rr) * 64 + wu]) * sclz + biaz;
        float zz = 1.0f / (1.0f + __expf(-prz));
        float hc = fmaxf(prh, 0.0f) * PKEEP;
        float hv = zz * hown[rr] + (1.0f - zz) * hc;
        hown[rr] = hv;
        hn4[rr] = hv;
      }
    }
#pragma unroll
    for (int rr = 0; rr < 4; ++rr) on4[rr] = __shfl_xor(hn4[rr], 1);

    // 6. let only P[t+2] ride; everything older (incl. P[t+1]) proven drained
    asm volatile("s_waitcnt vmcnt(1)" ::: "memory");

    if (lane < 16 && (lane & 1) == 0) {
      unsigned long long* hbn = hrec + (((size_t)(g * 2 + ((t + 1) & 1))) << 11);
      unsigned tagw = (unsigned)(t + 1);
#pragma unroll
      for (int rr = 0; rr < 4; ++rr) {
        unsigned long long rcd = ((unsigned long long)tagw << 32)
                               | (unsigned)f2bf(hn4[rr]) | ((unsigned)f2bf(on4[rr]) << 16);
        if (fastp)
          *(volatile unsigned long long*)(hbn + rr * 512 + (uu >> 1)) = rcd;
        else
          __hip_atomic_store(hbn + rr * 512 + (uu >> 1), rcd,
                             __ATOMIC_RELAXED, __HIP_MEMORY_SCOPE_SYSTEM);
      }
#pragma unroll
      for (int rr = 0; rr < 4; ++rr) {
        float2 ov = {hn4[rr], on4[rr]};
        *(float2*)(out + (size_t)(t * 32 + b0 + rr) * 1024 + uu) = ov;
      }
    }
    cur = cur + 1; if (cur >= 3) cur = 0;
  }
}

// ---------------- launch ----------------
extern "C" void kernel_launch(void* const* d_in, const int* in_sizes, int n_in,
                              void* d_out, int out_size, void* d_ws, size_t ws_size,
                              hipStream_t stream) {
  (void)in_sizes; (void)n_in; (void)out_size; (void)ws_size;
  const float* x   = (const float*)d_in[0];
  const float* Wh  = (const float*)d_in[1];
  const float* Wz  = (const float*)d_in[2];
  const float* Uh  = (const float*)d_in[3];
  const float* Uz  = (const float*)d_in[4];
  const float* gwh = (const float*)d_in[5];
  const float* bwh = (const float*)d_in[6];
  const float* gwz = (const float*)d_in[7];
  const float* bwz = (const float*)d_in[8];

  char* ws = (char*)d_ws;
  float*              sums  = (float*)(ws + 0);                  // 8192 B
  float*              sumsq = (float*)(ws + 8192);               // 8192 B
  unsigned long long* hrec  = (unsigned long long*)(ws + 16384); // 262144 B
  unsigned int*       ctrl  = (unsigned int*)(ws + 278528);      // 128 B
  unsigned short*     Wb    = (unsigned short*)(ws + 278784);    // 2 MiB

  // zero stats + records + ctrl every call (graph-replay safe; tag=0 == valid h0=0)
  hipMemsetAsync(d_ws, 0, 278784, stream);
  k_convw<<<1024, 256, 0, stream>>>(Wh, Wz, Wb);
  // P (bf16) lives in d_out; scan overwrites it with f32 output in provably-ordered fashion
  k_gemm<<<8000, 256, 0, stream>>>(x, Wb, (unsigned short*)d_out, sums, sumsq);
  k_scan<<<NW, 256, 0, stream>>>(Uh, Uz, gwh, bwh, gwz, bwz,
                                 (const unsigned short*)d_out, sums, sumsq,
                                 hrec, ctrl, (float*)d_out);
}

// Round 5
// 7817.509 us; speedup vs baseline: 1.4067x; 1.4067x over previous
//
#include <hip/hip_runtime.h>

// liGRU on MI355X.
// Phase 1: P[64000][2048](bf16, in d_out) = x @ [Wh;Wz]^T + column sums/sumsq.
// Phase 2: persistent scan, 8 groups (4 batch rows) x 32 WGs, 4 waves/WG.
//          Each wave owns 8 units and computes BOTH gates via packed MFMA B:
//          B cols 0-7 = Uz rows, cols 8-15 = Uh rows of the same units
//          (bfrag[32] = 128 VGPRs, same as round 2 -- no spills, unlike the
//          round-3 register-doubling attempt). z meets h via __shfl_xor(pre,8):
//          NO zlds, NO second barrier.
//          Exchange protocol = round-2 verbatim: system-scope u64 records
//          { tag=t+1 (hi32) | 2x bf16 h (lo32) } -- flag IS the data.
//          (Round-4 lesson: no hand-written sc0/sc1 cache-bit asm -- a sc0-only
//          poll can spin on a stale L1 line forever. Compiler-scoped atomics only.)
//          One raw s_barrier per step (lgkmcnt-only drain) + hlds double-buffered
//          by parity -> depth-2 register P-prefetch rides across barrier+stores;
//          the poll's explicit vmcnt(0) preserves the WAR proof on d_out:
//          P[t+1] drained (poll of step t) happens-before tag(t+1) store
//          happens-before any consumer writes out rows t+1 (step t+1).

#define T_STEPS 2000
#define NCOLS   2048
#define PKEEP   0.8f
#define BN_EPSF 1e-5f
#define NW      256

typedef __attribute__((ext_vector_type(8))) short bf16x8;
typedef __attribute__((ext_vector_type(4))) float f32x4;
typedef __attribute__((ext_vector_type(4))) unsigned int u32x4;

static __device__ __forceinline__ unsigned short f2bf(float f) {
  unsigned u = __builtin_bit_cast(unsigned, f);
  unsigned r = u + 0x7FFFu + ((u >> 16) & 1u);   // RNE
  return (unsigned short)(r >> 16);
}
static __device__ __forceinline__ float bf2f(unsigned short s) {
  unsigned u = ((unsigned)s) << 16;
  return __builtin_bit_cast(float, u);
}

// ---------------- K1: convert [Wh;Wz] f32 -> bf16 ----------------
__global__ void k_convw(const float* __restrict__ Wh, const float* __restrict__ Wz,
                        unsigned short* __restrict__ Wb) {
  int i = blockIdx.x * 256 + threadIdx.x;
  int e = i * 4;
  int n = e >> 9;
  int k = e & 511;
  const float* src = (n < 1024) ? (Wh + (size_t)n * 512 + k)
                                : (Wz + (size_t)(n - 1024) * 512 + k);
  float4 v = *(const float4*)src;
  *(ushort4*)(Wb + e) = make_ushort4(f2bf(v.x), f2bf(v.y), f2bf(v.z), f2bf(v.w));
}

// ---------------- K2: GEMM  P = x @ Wb^T  (+ BN stats) ----------------
__global__ __launch_bounds__(256, 2) void k_gemm(
    const float* __restrict__ X, const unsigned short* __restrict__ Wb,
    unsigned short* __restrict__ P, float* __restrict__ sums, float* __restrict__ sumsq) {
  __shared__ __align__(16) unsigned short As[128 * 32];
  __shared__ __align__(16) unsigned short Bs[128 * 32];
  const int tid  = threadIdx.x;
  const int bm   = blockIdx.x >> 4, bn = blockIdx.x & 15;
  const int lane = tid & 63, wid = tid >> 6;
  const int wm   = wid >> 1, wn = wid & 1;
  const int lrow = lane & 15, lk = lane >> 4;

  f32x4 acc[4][4] = {};

  for (int kk = 0; kk < 512; kk += 32) {
    __syncthreads();
#pragma unroll
    for (int j = 0; j < 2; ++j) {
      int c = j * 256 + wid * 64 + lane;
      int brow = c >> 2, b8 = (c & 3) * 8;
      const unsigned short* gp = Wb + (size_t)(bn * 128 + brow) * 512 + kk + b8;
      __builtin_amdgcn_global_load_lds(
          (const __attribute__((address_space(1))) unsigned int*)gp,
          (__attribute__((address_space(3))) unsigned int*)(Bs + (size_t)(j * 256 + wid * 64) * 8),
          16, 0, 0);
    }
    {
      int arow = tid >> 1, ahalf = tid & 1;
      const float4* xp = (const float4*)(X + (size_t)(bm * 128 + arow) * 512 + kk + ahalf * 16);
      unsigned v[8];
#pragma unroll
      for (int j = 0; j < 4; ++j) {
        float4 f = xp[j];
        v[j * 2 + 0] = (unsigned)f2bf(f.x) | ((unsigned)f2bf(f.y) << 16);
        v[j * 2 + 1] = (unsigned)f2bf(f.z) | ((unsigned)f2bf(f.w) << 16);
      }
      u32x4* ap = (u32x4*)(As + arow * 32 + ahalf * 16);
      u32x4 t0 = {v[0], v[1], v[2], v[3]};
      u32x4 t1 = {v[4], v[5], v[6], v[7]};
      ap[0] = t0; ap[1] = t1;
    }
    __syncthreads();

    bf16x8 af[4], bfr[4];
#pragma unroll
    for (int mt = 0; mt < 4; ++mt)
      af[mt] = *(const bf16x8*)(As + (wm * 64 + mt * 16 + lrow) * 32 + lk * 8);
#pragma unroll
    for (int nt = 0; nt < 4; ++nt)
      bfr[nt] = *(const bf16x8*)(Bs + (wn * 64 + nt * 16 + lrow) * 32 + lk * 8);
#pragma unroll
    for (int mt = 0; mt < 4; ++mt)
#pragma unroll
      for (int nt = 0; nt < 4; ++nt)
        acc[mt][nt] = __builtin_amdgcn_mfma_f32_16x16x32_bf16(af[mt], bfr[nt], acc[mt][nt], 0, 0, 0);
  }

#pragma unroll
  for (int mt = 0; mt < 4; ++mt)
#pragma unroll
    for (int nt = 0; nt < 4; ++nt) {
      f32x4 a = acc[mt][nt];
      int gcol  = bn * 128 + wn * 64 + nt * 16 + lrow;
      int grow0 = bm * 128 + wm * 64 + mt * 16 + lk * 4;
#pragma unroll
      for (int rr = 0; rr < 4; ++rr)
        P[(size_t)(grow0 + rr) * NCOLS + gcol] = f2bf(a[rr]);
    }
#pragma unroll
  for (int nt = 0; nt < 4; ++nt) {
    float s = 0.f, q = 0.f;
#pragma unroll
    for (int mt = 0; mt < 4; ++mt) {
      f32x4 a = acc[mt][nt];
#pragma unroll
      for (int rr = 0; rr < 4; ++rr) { s += a[rr]; q += a[rr] * a[rr]; }
    }
    s += __shfl_xor(s, 16); s += __shfl_xor(s, 32);
    q += __shfl_xor(q, 16); q += __shfl_xor(q, 32);
    if (lane < 16) {
      int gcol = bn * 128 + wn * 64 + nt * 16 + lrow;
      atomicAdd(&sums[gcol], s);
      atomicAdd(&sumsq[gcol], q);
    }
  }
}

// ---------------- K3: persistent scan ----------------
__global__ __launch_bounds__(256, 1) void k_scan(
    const float* __restrict__ Uh, const float* __restrict__ Uz,
    const float* __restrict__ gwh, const float* __restrict__ bwh,
    const float* __restrict__ gwz, const float* __restrict__ bwz,
    const unsigned short* P,            // aliases d_out (bf16 view) -- no restrict!
    const float* __restrict__ sums, const float* __restrict__ sumsq,
    unsigned long long* hrec,           // [8][2][2048] u64 records
    unsigned int* ctrl,                 // [0]=rendezvous counter
    float* out)                         // aliases d_out (f32 view) -- no restrict!
{
  // hlds double-buffered by step parity: [2][4 rows][1024 units] bf16, XOR-swizzled
  __shared__ __align__(16) unsigned char hlds[16384];

  const int tid  = threadIdx.x;
  const int lane = tid & 63;
  const int wid  = tid >> 6;
  const int lrow = lane & 15, lk = lane >> 4;

  const int g    = blockIdx.x & 7;       // group = 4 batch rows
  const int role = blockIdx.x >> 3;      // [0,32): unit block
  const int b0   = g * 4;
  const int u0w  = role * 32 + wid * 8;  // this wave's 8 units
  const bool isH = (lrow >= 8);          // B col 0-7 = z, 8-15 = h
  const int unit = u0w + (lrow & 7);
  const int col  = isH ? unit : (1024 + unit);   // P column for this lane's gate

  // ---- BatchNorm scale/bias for this lane's column ----
  float scl, bia;
  {
    float s = sums[col], q = sumsq[col];
    float gam = isH ? gwh[unit] : gwz[unit];
    float bet = isH ? bwh[unit] : bwz[unit];
    float mean = s * (1.0f / 64000.0f);
    float var  = q * (1.0f / 64000.0f) - mean * mean;
    float rstd = rsqrtf(var + BN_EPSF);
    scl = gam * rstd;
    bia = bet - mean * scl;
  }

  // ---- preload this lane's U row (x PKEEP) as 32 MFMA B-fragments (128 VGPRs)
  //      packed: B rows 0-7 = Uz[u0w..], rows 8-15 = Uh[u0w..]
  const float* urow = (isH ? Uh : Uz) + (size_t)unit * 1024;
  bf16x8 bfrag[32];
#pragma unroll
  for (int kt = 0; kt < 32; ++kt) {
    const float4* p4 = (const float4*)(urow + kt * 32 + lk * 8);
    float4 fa = p4[0], fb = p4[1];
    bf16x8 tv;
    tv[0] = (short)f2bf(fa.x * PKEEP); tv[1] = (short)f2bf(fa.y * PKEEP);
    tv[2] = (short)f2bf(fa.z * PKEEP); tv[3] = (short)f2bf(fa.w * PKEEP);
    tv[4] = (short)f2bf(fb.x * PKEEP); tv[5] = (short)f2bf(fb.y * PKEEP);
    tv[6] = (short)f2bf(fb.z * PKEEP); tv[7] = (short)f2bf(fb.w * PKEEP);
    bfrag[kt] = tv;
  }

  // ---- P prefetch prologue: pf=P[0], pn1=P[1] ----
  unsigned short pf[4], pn1[4];
#pragma unroll
  for (int rr = 0; rr < 4; ++rr) {
    pf[rr]  = P[(size_t)(b0 + rr) * NCOLS + col];
    pn1[rr] = P[(size_t)(32 + b0 + rr) * NCOLS + col];
  }
  __syncthreads();   // full drain: my initial P loads complete

  // ---- rendezvous: ALL WGs' initial P loads drained before anyone can write
  //      out rows 0/1 (WAR on the d_out aliasing). Fixes the r1/r2 latent race.
  if (tid == 0) {
    __hip_atomic_fetch_add(&ctrl[0], 1u, __ATOMIC_RELEASE, __HIP_MEMORY_SCOPE_SYSTEM);
    while (__hip_atomic_load(&ctrl[0], __ATOMIC_RELAXED, __HIP_MEMORY_SCOPE_SYSTEM) < NW)
      __builtin_amdgcn_s_sleep(8);
  }
  __syncthreads();

  f32x4 hown = {0.f, 0.f, 0.f, 0.f};

  for (int t = 0; t < T_STEPS; ++t) {
    const int par = t & 1;

    // ---- 1. poll this thread's 8 records (parity par); tag carries the data.
    //      Round-2-proven system-scope protocol.
    const unsigned long long* rb = hrec + (((size_t)(g * 2 + par)) << 11) + tid;
    unsigned long long rec[8];
#pragma unroll
    for (int j = 0; j < 8; ++j)
      rec[j] = __hip_atomic_load(rb + 256 * j, __ATOMIC_RELAXED, __HIP_MEMORY_SCOPE_SYSTEM);
    while (true) {
      unsigned bad = 0;
#pragma unroll
      for (int j = 0; j < 8; ++j)
        if ((unsigned)(rec[j] >> 32) < (unsigned)t) bad |= (1u << j);
      if (!bad) break;
      __builtin_amdgcn_s_sleep(1);
#pragma unroll
      for (int j = 0; j < 8; ++j)
        if (bad & (1u << j))
          rec[j] = __hip_atomic_load(rb + 256 * j, __ATOMIC_RELAXED, __HIP_MEMORY_SCOPE_SYSTEM);
    }
    // full vmem drain: pins "P[t+1] (issued last step) completed" -> WAR proof
    asm volatile("s_waitcnt vmcnt(0)" ::: "memory");

    // ---- 2. prefetch P[t+2]: rides across barrier + all stores until next poll
    unsigned short pn2[4] = {0, 0, 0, 0};
    if (t + 2 < T_STEPS) {
#pragma unroll
      for (int rr = 0; rr < 4; ++rr)
        pn2[rr] = P[(size_t)((t + 2) * 32 + b0 + rr) * NCOLS + col];
    }

    // ---- 3. unpack h records into hlds[par] (XOR-swizzled) ----
    unsigned char* hb = hlds + par * 8192;
#pragma unroll
    for (int j = 0; j < 8; ++j) {
      int idx = tid + 256 * j;
      int row = idx >> 9, up = idx & 511;
      int byteoff = (row * 2048 + up * 4) ^ ((row & 3) << 5);
      *(unsigned*)(hb + byteoff) = (unsigned)rec[j];
    }
    // single raw barrier per step: LDS-only drain; P[t+2] stays in flight
    asm volatile("s_waitcnt lgkmcnt(0)" ::: "memory");
    __builtin_amdgcn_sched_barrier(0);
    __builtin_amdgcn_s_barrier();
    __builtin_amdgcn_sched_barrier(0);

    // ---- 4. packed dot: one MFMA stream computes BOTH gates ----
    f32x4 ac0 = {0.f, 0.f, 0.f, 0.f}, ac1 = ac0, ac2 = ac0, ac3 = ac0;
#pragma unroll
    for (int kt = 0; kt < 32; ++kt) {
      int ab = ((lane & 3) * 2048 + kt * 64 + lk * 16) ^ ((lane & 3) << 5);
      bf16x8 af = *(const bf16x8*)(hb + ab);
      if ((kt & 3) == 0)      ac0 = __builtin_amdgcn_mfma_f32_16x16x32_bf16(af, bfrag[kt], ac0, 0, 0, 0);
      else if ((kt & 3) == 1) ac1 = __builtin_amdgcn_mfma_f32_16x16x32_bf16(af, bfrag[kt], ac1, 0, 0, 0);
      else if ((kt & 3) == 2) ac2 = __builtin_amdgcn_mfma_f32_16x16x32_bf16(af, bfrag[kt], ac2, 0, 0, 0);
      else                    ac3 = __builtin_amdgcn_mfma_f32_16x16x32_bf16(af, bfrag[kt], ac3, 0, 0, 0);
    }
    f32x4 dsum = (ac0 + ac1) + (ac2 + ac3);

    // ---- 5. epilogue: z meets h via shfl_xor(8); lanes 8-15 own the update ----
    float pre[4], oth[4];
#pragma unroll
    for (int rr = 0; rr < 4; ++rr) {
      pre[rr] = dsum[rr] + bf2f(pf[rr]) * scl + bia;
      oth[rr] = __shfl_xor(pre[rr], 8);     // all lanes participate
    }

    if (lk == 0 && isH) {                    // lanes 8..15: pre=h-pre, oth=z-pre
      float hn[4];
#pragma unroll
      for (int rr = 0; rr < 4; ++rr) {
        float zz = 1.0f / (1.0f + __expf(-oth[rr]));
        float hc = fmaxf(pre[rr], 0.0f) * PKEEP;      // relu * 'orig' dropout
        hn[rr] = zz * hown[rr] + (1.0f - zz) * hc;
        hown[rr] = hn[rr];
      }
      float pp[4];
#pragma unroll
      for (int rr = 0; rr < 4; ++rr) pp[rr] = __shfl_xor(hn[rr], 1);  // lanes 8-15 active
      if ((lane & 1) == 0) {                 // lanes 8,10,12,14: units even
        unsigned long long* hbn = hrec + (((size_t)(g * 2 + ((t + 1) & 1))) << 11)
                                + (unit >> 1);
        unsigned tagw = (unsigned)(t + 1);
#pragma unroll
        for (int rr = 0; rr < 4; ++rr) {
          unsigned long long rcd = ((unsigned long long)tagw << 32)
                                 | (unsigned)f2bf(hn[rr]) | ((unsigned)f2bf(pp[rr]) << 16);
          __hip_atomic_store(hbn + rr * 512, rcd,
                             __ATOMIC_RELAXED, __HIP_MEMORY_SCOPE_SYSTEM);
        }
#pragma unroll
        for (int rr = 0; rr < 4; ++rr) {
          float2 ov = {hn[rr], pp[rr]};
          *(float2*)(out + (size_t)(t * 32 + b0 + rr) * 1024 + unit) = ov;
        }
      }
    }

#pragma unroll
    for (int rr = 0; rr < 4; ++rr) { pf[rr] = pn1[rr]; pn1[rr] = pn2[rr]; }
  }
}

// ---------------- launch ----------------
extern "C" void kernel_launch(void* const* d_in, const int* in_sizes, int n_in,
                              void* d_out, int out_size, void* d_ws, size_t ws_size,
                              hipStream_t stream) {
  (void)in_sizes; (void)n_in; (void)out_size; (void)ws_size;
  const float* x   = (const float*)d_in[0];
  const float* Wh  = (const float*)d_in[1];
  const float* Wz  = (const float*)d_in[2];
  const float* Uh  = (const float*)d_in[3];
  const float* Uz  = (const float*)d_in[4];
  const float* gwh = (const float*)d_in[5];
  const float* bwh = (const float*)d_in[6];
  const float* gwz = (const float*)d_in[7];
  const float* bwz = (const float*)d_in[8];

  char* ws = (char*)d_ws;
  float*              sums  = (float*)(ws + 0);                  // 8192 B
  float*              sumsq = (float*)(ws + 8192);               // 8192 B
  unsigned long long* hrec  = (unsigned long long*)(ws + 16384); // 262144 B
  unsigned int*       ctrl  = (unsigned int*)(ws + 278528);      // 128 B
  unsigned short*     Wb    = (unsigned short*)(ws + 278784);    // 2 MiB

  // zero stats + records + ctrl every call (graph-replay safe; tag=0 == valid h0=0)
  hipMemsetAsync(d_ws, 0, 278784, stream);
  k_convw<<<1024, 256, 0, stream>>>(Wh, Wz, Wb);
  // P (bf16) lives in d_out; scan overwrites it with f32 output in provably-ordered fashion
  k_gemm<<<8000, 256, 0, stream>>>(x, Wb, (unsigned short*)d_out, sums, sumsq);
  k_scan<<<NW, 256, 0, stream>>>(Uh, Uz, gwh, bwh, gwz, bwz,
                                 (const unsigned short*)d_out, sums, sumsq,
                                 hrec, ctrl, (float*)d_out);
}